// Round 7
// baseline (964.292 us; speedup 1.0000x reference)
//
#include <hip/hip_runtime.h>
#include <hip/hip_bf16.h>

#define N_NODES 50000
#define M_EDGES 800000
#define LEAKY_F 0.2f
#define BN_EPS 1e-5f

__device__ __forceinline__ float leaky(float x) { return x >= 0.f ? x : LEAKY_F * x; }

// round-to-nearest-even f32 -> bf16 (finite inputs)
__device__ __forceinline__ unsigned f2bf(float f) {
  unsigned u = __float_as_uint(f);
  return (u + 0x7fffu + ((u >> 16) & 1u)) >> 16;
}
__device__ __forceinline__ unsigned packbf(float a, float b) {
  return (f2bf(b) << 16) | f2bf(a);
}
__device__ __forceinline__ float bflo(unsigned u) { return __uint_as_float(u << 16); }
__device__ __forceinline__ float bfhi(unsigned u) { return __uint_as_float(u & 0xffff0000u); }

// ================= CSR build =================
__global__ __launch_bounds__(256) void hist_k(const int* __restrict__ dst,
                                              int* __restrict__ counts) {
  int e = blockIdx.x * 256 + threadIdx.x;
  if (e < M_EDGES) atomicAdd(&counts[dst[e]], 1);
}

__global__ __launch_bounds__(256) void scan_k(const int* __restrict__ counts,
                                              int* __restrict__ offs,
                                              int* __restrict__ cursor) {
  __shared__ int chunk[256];
  const int CH = (N_NODES + 255) / 256;
  int tid = threadIdx.x;
  int beg = tid * CH, end = min(beg + CH, N_NODES);
  int s = 0;
  for (int i = beg; i < end; ++i) s += counts[i];
  chunk[tid] = s;
  __syncthreads();
  if (tid == 0) {
    int run = 0;
    for (int i = 0; i < 256; ++i) { int c = chunk[i]; chunk[i] = run; run += c; }
  }
  __syncthreads();
  int base = chunk[tid];
  for (int i = beg; i < end; ++i) {
    offs[i] = base;
    cursor[i] = base;
    base += counts[i];
  }
  if (tid == 0) offs[N_NODES] = M_EDGES;
}

// CSR fill: dst-sorted src list + original edge id + dst value per CSR slot
__global__ __launch_bounds__(256) void fill_k(const int* __restrict__ src,
                                              const int* __restrict__ dst,
                                              int* __restrict__ cursor,
                                              int* __restrict__ ssrc,
                                              int* __restrict__ eid,
                                              int* __restrict__ sdst) {
  int e = blockIdx.x * 256 + threadIdx.x;
  if (e >= M_EDGES) return;
  int d = dst[e];
  int p = atomicAdd(&cursor[d], 1);
  ssrc[p] = src[e];
  eid[p] = e;
  sdst[p] = d;
}

// ---- segment gather-sum, wave per node, 4x unrolled ----
__global__ __launch_bounds__(256) void gather_seg_k(const float* __restrict__ X,
                                                    const int* __restrict__ offs,
                                                    const int* __restrict__ ssrc,
                                                    float* __restrict__ O) {
  int n = blockIdx.x * 4 + (threadIdx.x >> 6);
  int j = threadIdx.x & 63;
  int beg = offs[n], end = offs[n + 1];
  float acc = 0.f;
  int i = beg;
  for (; i + 3 < end; i += 4) {
    int s0 = ssrc[i], s1 = ssrc[i + 1], s2 = ssrc[i + 2], s3 = ssrc[i + 3];
    float a = X[(size_t)s0 * 64 + j];
    float b = X[(size_t)s1 * 64 + j];
    float c = X[(size_t)s2 * 64 + j];
    float d = X[(size_t)s3 * 64 + j];
    acc += (a + b) + (c + d);
  }
  for (; i < end; ++i) acc += X[(size_t)ssrc[i] * 64 + j];
  O[(size_t)n * 64 + j] = acc;
}

// ================= weight-prep (algebraic collapse) =================
__global__ __launch_bounds__(256) void prep1_k(const float* __restrict__ W_ops,
                                               const float* __restrict__ W_cat,
                                               float* __restrict__ W12g,
                                               float* __restrict__ Wc12g) {
  __shared__ float Wa[4096], Wb[4096];
  int tid = threadIdx.x;
  const float *Am, *Bm, *Add;
  float* Out;
  if (blockIdx.x == 0) { Am = W_ops; Bm = W_ops + 8192; Add = W_ops + 4096; Out = W12g; }
  else { Am = W_ops + 16384; Bm = W_cat + 8192; Add = W_cat + 4096; Out = Wc12g; }
  for (int i = tid; i < 4096; i += 256) { Wa[i] = Am[i]; Wb[i] = Bm[i]; }
  __syncthreads();
  for (int t = 0; t < 16; ++t) {
    int o = tid + t * 256;
    int r = o >> 6, j = o & 63;
    float acc = Add[o];
#pragma unroll
    for (int k = 0; k < 64; ++k) acc = fmaf(Wa[r * 64 + k], Wb[k * 64 + j], acc);
    Out[o] = acc;
  }
}

__global__ __launch_bounds__(256) void prep2_k(const float* __restrict__ W_ops,
                                               const float* __restrict__ b_ops,
                                               const float* __restrict__ W_cat,
                                               const float* __restrict__ b_cat,
                                               const float* __restrict__ W12g,
                                               const float* __restrict__ Wc12g,
                                               float* __restrict__ WAg,
                                               float* __restrict__ WBg,
                                               float* __restrict__ cg) {
  __shared__ float M0[4096], M1[4096], M2[4096], M3[4096], M4[4096];
  __shared__ float bb[64];
  int tid = threadIdx.x;
  if (blockIdx.x == 0) {
    for (int i = tid; i < 4096; i += 256) {
      M0[i] = W_ops[i];
      M1[i] = W_cat[i];
      M2[i] = W12g[i];
      M3[i] = Wc12g[i];
    }
    __syncthreads();
    for (int t = 0; t < 16; ++t) {
      int o = tid + t * 256;
      int r = o >> 6, j = o & 63;
      float acc = 0.f;
#pragma unroll
      for (int k = 0; k < 64; ++k) {
        acc = fmaf(M0[r * 64 + k], M1[k * 64 + j], acc);
        acc = fmaf(M2[r * 64 + k], M3[k * 64 + j], acc);
      }
      WAg[o] = acc;
    }
  } else {
    for (int i = tid; i < 4096; i += 256) {
      M0[i] = W_ops[3 * 4096 + i];
      M1[i] = W_cat[8192 + i];
      M2[i] = W_ops[2 * 4096 + i];
      M3[i] = W_cat[i];
      M4[i] = Wc12g[i];
    }
    __syncthreads();
    for (int t = 0; t < 16; ++t) {
      int o = tid + t * 256;
      int r = o >> 6, j = o & 63;
      float acc = 0.f;
#pragma unroll
      for (int k = 0; k < 64; ++k) acc = fmaf(M0[r * 64 + k], M1[k * 64 + j], acc);
      WBg[o] = acc;
    }
    if (tid < 64) {
      int j = tid;
      float acc = b_ops[64 + j] + b_ops[128 + j];
#pragma unroll
      for (int k = 0; k < 64; ++k) acc = fmaf(b_ops[k], M2[k * 64 + j], acc);
      bb[j] = acc;
    }
    __syncthreads();
    if (tid < 64) {
      int j = tid;
      float acc = b_cat[j];
#pragma unroll
      for (int k = 0; k < 64; ++k) {
        acc = fmaf(b_ops[k], M3[k * 64 + j], acc);
        acc = fmaf(bb[k], M4[k * 64 + j], acc);
        acc = fmaf(b_ops[192 + k] + b_ops[256 + k], M1[k * 64 + j], acc);
      }
      cg[j] = acc;
    }
  }
}

// ================= row-register matmul kernels =================
__global__ __launch_bounds__(256) void rowmm1_k(const float* __restrict__ A,
                                                const float* __restrict__ W_ops,
                                                const float* __restrict__ b_ops,
                                                float* __restrict__ s1) {
  __shared__ float W[4096];
  __shared__ float bias[64];
  int tid = threadIdx.x;
  for (int i = tid; i < 4096; i += 256) W[i] = W_ops[i];
  if (tid < 64) bias[tid] = b_ops[tid];
  __syncthreads();
  int r = blockIdx.x * 256 + tid;
  if (r >= N_NODES) return;
  float x[64];
  const float4* Xr = reinterpret_cast<const float4*>(A + (size_t)r * 64);
#pragma unroll
  for (int q = 0; q < 16; ++q) {
    float4 v = Xr[q];
    x[q * 4] = v.x; x[q * 4 + 1] = v.y; x[q * 4 + 2] = v.z; x[q * 4 + 3] = v.w;
  }
  float4* Or = reinterpret_cast<float4*>(s1 + (size_t)r * 64);
  for (int j0 = 0; j0 < 64; j0 += 4) {
    float a0 = bias[j0], a1 = bias[j0 + 1], a2 = bias[j0 + 2], a3 = bias[j0 + 3];
#pragma unroll
    for (int k = 0; k < 64; ++k) {
      float4 w = *reinterpret_cast<const float4*>(&W[k * 64 + j0]);
      a0 = fmaf(x[k], w.x, a0);
      a1 = fmaf(x[k], w.y, a1);
      a2 = fmaf(x[k], w.z, a2);
      a3 = fmaf(x[k], w.w, a3);
    }
    Or[j0 >> 2] = make_float4(a0, a1, a2, a3);
  }
}

__global__ __launch_bounds__(256) void vnew_k(const float* __restrict__ A,
                                              const float* __restrict__ B,
                                              const float* __restrict__ WAg,
                                              const float* __restrict__ WBg,
                                              const float* __restrict__ cg,
                                              float* __restrict__ Vnew) {
  __shared__ float WA[4096], WB[4096];
  __shared__ float cb[64];
  int tid = threadIdx.x;
  for (int i = tid; i < 4096; i += 256) { WA[i] = WAg[i]; WB[i] = WBg[i]; }
  if (tid < 64) cb[tid] = cg[tid];
  __syncthreads();
  int r = blockIdx.x * 256 + tid;
  if (r >= N_NODES) return;
  float xa[64], xb[64];
  const float4* Ar = reinterpret_cast<const float4*>(A + (size_t)r * 64);
  const float4* Br = reinterpret_cast<const float4*>(B + (size_t)r * 64);
#pragma unroll
  for (int q = 0; q < 16; ++q) {
    float4 va = Ar[q];
    xa[q * 4] = va.x; xa[q * 4 + 1] = va.y; xa[q * 4 + 2] = va.z; xa[q * 4 + 3] = va.w;
    float4 vb = Br[q];
    xb[q * 4] = vb.x; xb[q * 4 + 1] = vb.y; xb[q * 4 + 2] = vb.z; xb[q * 4 + 3] = vb.w;
  }
  float4* Or = reinterpret_cast<float4*>(Vnew + (size_t)r * 64);
  for (int j0 = 0; j0 < 64; j0 += 4) {
    float a0 = cb[j0], a1 = cb[j0 + 1], a2 = cb[j0 + 2], a3 = cb[j0 + 3];
#pragma unroll
    for (int k = 0; k < 64; ++k) {
      float4 wa = *reinterpret_cast<const float4*>(&WA[k * 64 + j0]);
      a0 = fmaf(xa[k], wa.x, a0);
      a1 = fmaf(xa[k], wa.y, a1);
      a2 = fmaf(xa[k], wa.z, a2);
      a3 = fmaf(xa[k], wa.w, a3);
      float4 wb = *reinterpret_cast<const float4*>(&WB[k * 64 + j0]);
      a0 = fmaf(xb[k], wb.x, a0);
      a1 = fmaf(xb[k], wb.y, a1);
      a2 = fmaf(xb[k], wb.z, a2);
      a3 = fmaf(xb[k], wb.w, a3);
    }
    Or[j0 >> 2] = make_float4(a0, a1, a2, a3);
  }
}

// Ps/Pd written as packed bf16 pairs (row = 32 uints = 128 B)
__global__ __launch_bounds__(256) void proj_k(const float* __restrict__ Vnew,
                                              const float* __restrict__ W_S,
                                              const float* __restrict__ b_S,
                                              unsigned* __restrict__ PsP,
                                              unsigned* __restrict__ PdP) {
  __shared__ float W0s[4096], W2s[4096];
  __shared__ float bias[64];
  int tid = threadIdx.x;
  for (int i = tid; i < 4096; i += 256) { W0s[i] = W_S[i]; W2s[i] = W_S[8192 + i]; }
  if (tid < 64) bias[tid] = b_S[tid];
  __syncthreads();
  int r = blockIdx.x * 256 + tid;
  if (r >= N_NODES) return;
  float x[64];
  const float4* Xr = reinterpret_cast<const float4*>(Vnew + (size_t)r * 64);
#pragma unroll
  for (int q = 0; q < 16; ++q) {
    float4 v = Xr[q];
    x[q * 4] = v.x; x[q * 4 + 1] = v.y; x[q * 4 + 2] = v.z; x[q * 4 + 3] = v.w;
  }
  for (int j0 = 0; j0 < 64; j0 += 4) {
    float a0 = bias[j0], a1 = bias[j0 + 1], a2 = bias[j0 + 2], a3 = bias[j0 + 3];
    float d0 = 0.f, d1 = 0.f, d2 = 0.f, d3 = 0.f;
#pragma unroll
    for (int k = 0; k < 64; ++k) {
      float xk = x[k];
      float4 w = *reinterpret_cast<const float4*>(&W0s[k * 64 + j0]);
      a0 = fmaf(xk, w.x, a0);
      a1 = fmaf(xk, w.y, a1);
      a2 = fmaf(xk, w.z, a2);
      a3 = fmaf(xk, w.w, a3);
      float4 u = *reinterpret_cast<const float4*>(&W2s[k * 64 + j0]);
      d0 = fmaf(xk, u.x, d0);
      d1 = fmaf(xk, u.y, d1);
      d2 = fmaf(xk, u.z, d2);
      d3 = fmaf(xk, u.w, d3);
    }
    uint2 ps = make_uint2(packbf(a0, a1), packbf(a2, a3));
    uint2 pd = make_uint2(packbf(d0, d1), packbf(d2, d3));
    *reinterpret_cast<uint2*>(&PsP[(size_t)r * 32 + (j0 >> 1)]) = ps;
    *reinterpret_cast<uint2*>(&PdP[(size_t)r * 32 + (j0 >> 1)]) = pd;
  }
}

// ---- edge in dst-CSR order with COOPERATIVE row-granular gather:
// 16-lane groups load whole packed Ps/Pd rows (2 lines/row instead of 16
// per-lane requests), sum in f32 into Spd LDS; FMA loop unchanged; fused stats.
__global__ __launch_bounds__(256) void edge_k(
    const float* __restrict__ Eg, const int* __restrict__ ssrc, const int* __restrict__ sdst,
    const int* __restrict__ eid,
    const unsigned* __restrict__ PsP, const unsigned* __restrict__ PdP,
    const float* __restrict__ W_S, float* __restrict__ Eout, float* __restrict__ stats) {
  __shared__ unsigned Wt[64][33];   // Wt[j][k2] = bf16 pair (Wm[2k2][j], Wm[2k2+1][j])
  __shared__ unsigned Ea[64][33];   // Ea[e][k2] = bf16 pair of leaky(E) row
  __shared__ float Spd[64][68];     // Spd[e][j] = Ps[src[e]][j] + Pd[dst[e]][j]
  __shared__ int leid[64];
  __shared__ float ls[128];
  int tid = threadIdx.x;
  int e0 = blockIdx.x * 64;
  int l16 = tid & 15, g16 = tid >> 4;

  // phase A: issue gather row-loads into regs (latency overlaps staging)
  uint2 pa[4], pb[4];
#pragma unroll
  for (int rr = 0; rr < 4; ++rr) {
    int p = e0 + rr * 16 + g16;
    int s = ssrc[p], d = sdst[p];
    pa[rr] = *reinterpret_cast<const uint2*>(&PsP[(size_t)s * 32 + 2 * l16]);
    pb[rr] = *reinterpret_cast<const uint2*>(&PdP[(size_t)d * 32 + 2 * l16]);
  }
  if (tid < 64) leid[tid] = eid[e0 + tid];
  for (int q = tid; q < 2048; q += 256) {
    int k2 = q >> 6, j = q & 63;
    float w0 = W_S[4096 + (2 * k2) * 64 + j];
    float w1 = W_S[4096 + (2 * k2 + 1) * 64 + j];
    Wt[j][k2] = packbf(w0, w1);
  }
  if (tid < 128) ls[tid] = 0.f;
  __syncthreads();

  // phase B: stage leaky(E) (indirect rows) + write gathered sums to Spd
  for (int q = tid; q < 1024; q += 256) {
    int e = q >> 4, kq = q & 15;
    float4 vv = reinterpret_cast<const float4*>(Eg)[(size_t)leid[e] * 16 + kq];
    Ea[e][kq * 2]     = packbf(leaky(vv.x), leaky(vv.y));
    Ea[e][kq * 2 + 1] = packbf(leaky(vv.z), leaky(vv.w));
  }
#pragma unroll
  for (int rr = 0; rr < 4; ++rr) {
    int r = rr * 16 + g16;
    float4 f;
    f.x = bflo(pa[rr].x) + bflo(pb[rr].x);
    f.y = bfhi(pa[rr].x) + bfhi(pb[rr].x);
    f.z = bflo(pa[rr].y) + bflo(pb[rr].y);
    f.w = bfhi(pa[rr].y) + bfhi(pb[rr].y);
    *reinterpret_cast<float4*>(&Spd[r][4 * l16]) = f;
  }
  __syncthreads();

  int eq = tid & 15, cq = tid >> 4;
  int eb = eq * 4;
  float acc[4][4];
#pragma unroll
  for (int i = 0; i < 4; ++i) {
    float4 f = *reinterpret_cast<const float4*>(&Spd[eb + i][4 * cq]);
    acc[i][0] = f.x; acc[i][1] = f.y; acc[i][2] = f.z; acc[i][3] = f.w;
  }

#pragma unroll 4
  for (int k2 = 0; k2 < 32; ++k2) {
    float w0[4], w1[4];
#pragma unroll
    for (int c = 0; c < 4; ++c) {
      unsigned u = Wt[cq * 4 + c][k2];
      w0[c] = bflo(u);
      w1[c] = bfhi(u);
    }
#pragma unroll
    for (int i = 0; i < 4; ++i) {
      unsigned ue = Ea[eb + i][k2];
      float ev0 = bflo(ue), ev1 = bfhi(ue);
#pragma unroll
      for (int c = 0; c < 4; ++c) {
        acc[i][c] = fmaf(ev0, w0[c], acc[i][c]);
        acc[i][c] = fmaf(ev1, w1[c], acc[i][c]);
      }
    }
  }

  float s4[4] = {0.f, 0.f, 0.f, 0.f}, q4[4] = {0.f, 0.f, 0.f, 0.f};
#pragma unroll
  for (int i = 0; i < 4; ++i) {
    float4 st = make_float4(acc[i][0], acc[i][1], acc[i][2], acc[i][3]);
    reinterpret_cast<float4*>(Eout)[(size_t)leid[eb + i] * 16 + cq] = st;
#pragma unroll
    for (int c = 0; c < 4; ++c) {
      s4[c] += acc[i][c];
      q4[c] = fmaf(acc[i][c], acc[i][c], q4[c]);
    }
  }
#pragma unroll
  for (int off = 8; off; off >>= 1) {
#pragma unroll
    for (int c = 0; c < 4; ++c) {
      s4[c] += __shfl_xor(s4[c], off, 16);
      q4[c] += __shfl_xor(q4[c], off, 16);
    }
  }
  if (eq == 0) {
#pragma unroll
    for (int c = 0; c < 4; ++c) {
      atomicAdd(&ls[cq * 4 + c], s4[c]);
      atomicAdd(&ls[64 + cq * 4 + c], q4[c]);
    }
  }
  __syncthreads();
  if (tid < 128) atomicAdd(&stats[tid], ls[tid]);
}

// ---- per-column sum / sumsq (for V side) ----
__global__ __launch_bounds__(256) void col_stats_k(
    const float* __restrict__ X, size_t nelem, float* __restrict__ sums) {
  __shared__ float ls[128];
  int tid = threadIdx.x;
  if (tid < 128) ls[tid] = 0.f;
  __syncthreads();
  int j = tid & 63;
  float s = 0.f, ss = 0.f;
  size_t stride = (size_t)gridDim.x * blockDim.x;
  for (size_t i = (size_t)blockIdx.x * blockDim.x + tid; i < nelem; i += stride) {
    float x = X[i];
    s += x;
    ss = fmaf(x, x, ss);
  }
  atomicAdd(&ls[j], s);
  atomicAdd(&ls[64 + j], ss);
  __syncthreads();
  if (tid < 128) atomicAdd(&sums[tid], ls[tid]);
}

__global__ void finalize_k(const float* __restrict__ sums, float inv_n,
                           const float* __restrict__ gamma, const float* __restrict__ beta,
                           float* __restrict__ sc_shift) {
  int j = threadIdx.x;
  float mu = sums[j] * inv_n;
  float var = sums[64 + j] * inv_n - mu * mu;
  float sc = gamma[j] * rsqrtf(var + BN_EPS);
  sc_shift[j] = sc;
  sc_shift[64 + j] = beta[j] - mu * sc;
}

__global__ __launch_bounds__(256) void bn_apply_k(
    float* __restrict__ X, const float* __restrict__ resid,
    const float* __restrict__ sc_shift, int n4) {
  int i = blockIdx.x * blockDim.x + threadIdx.x;
  if (i >= n4) return;
  int jq = i & 15;
  float4 x = reinterpret_cast<float4*>(X)[i];
  float4 r = reinterpret_cast<const float4*>(resid)[i];
  float4 sc = reinterpret_cast<const float4*>(sc_shift)[jq];
  float4 sh = reinterpret_cast<const float4*>(sc_shift + 64)[jq];
  float4 y;
  y.x = leaky(fmaf(x.x, sc.x, sh.x)) + r.x;
  y.y = leaky(fmaf(x.y, sc.y, sh.y)) + r.y;
  y.z = leaky(fmaf(x.z, sc.z, sh.z)) + r.z;
  y.w = leaky(fmaf(x.w, sc.w, sh.w)) + r.w;
  reinterpret_cast<float4*>(X)[i] = y;
}

extern "C" void kernel_launch(void* const* d_in, const int* in_sizes, int n_in,
                              void* d_out, int out_size, void* d_ws, size_t ws_size,
                              hipStream_t stream) {
  const float* V      = (const float*)d_in[0];
  const float* Eg     = (const float*)d_in[1];
  const int*   src    = (const int*)d_in[2];
  const int*   dst    = (const int*)d_in[3];
  const float* W_ops  = (const float*)d_in[4];
  const float* b_ops  = (const float*)d_in[5];
  const float* W_cat  = (const float*)d_in[6];
  const float* b_cat  = (const float*)d_in[7];
  const float* W_S    = (const float*)d_in[8];
  const float* b_S    = (const float*)d_in[9];
  const float* gammaV = (const float*)d_in[10];
  const float* betaV  = (const float*)d_in[11];
  const float* gammaE = (const float*)d_in[12];
  const float* betaE  = (const float*)d_in[13];

  float* ws = (float*)d_ws;
  const size_t ND = (size_t)N_NODES * 64;
  float* A    = ws;
  float* s1   = ws + ND;
  float* Bg   = ws + 2 * ND;
  unsigned* PsP = (unsigned*)(ws + 3 * ND);   // 50000*32 uints
  unsigned* PdP = (unsigned*)(ws + 4 * ND);
  float* xb   = ws + 5 * ND;
  float* W12g  = xb;
  float* Wc12g = xb + 4096;
  float* WAg   = xb + 8192;
  float* WBg   = xb + 12288;
  float* cg    = xb + 16384;
  float* statsV = xb + 16448;
  float* statsE = statsV + 128;
  float* scshV  = statsV + 256;
  float* scshE  = statsV + 384;
  int* counts = (int*)(statsV + 512);
  int* offs   = counts + N_NODES;
  int* cursor = offs + N_NODES + 1;
  int* ssrc   = cursor + N_NODES;
  int* eid    = ssrc + M_EDGES;
  int* sdst   = eid + M_EDGES;

  float* Vout  = (float*)d_out;
  float* EoutP = Vout + ND;

  hipMemsetAsync(counts, 0, N_NODES * sizeof(int), stream);
  hipMemsetAsync(statsV, 0, 256 * sizeof(float), stream);

  const int eb = (M_EDGES + 255) / 256;
  const int rb = (N_NODES + 255) / 256;
  prep1_k<<<2, 256, 0, stream>>>(W_ops, W_cat, W12g, Wc12g);
  prep2_k<<<2, 256, 0, stream>>>(W_ops, b_ops, W_cat, b_cat, W12g, Wc12g, WAg, WBg, cg);
  hist_k<<<eb, 256, 0, stream>>>(dst, counts);
  scan_k<<<1, 256, 0, stream>>>(counts, offs, cursor);
  fill_k<<<eb, 256, 0, stream>>>(src, dst, cursor, ssrc, eid, sdst);

  gather_seg_k<<<N_NODES / 4, 256, 0, stream>>>(V, offs, ssrc, A);
  rowmm1_k<<<rb, 256, 0, stream>>>(A, W_ops, b_ops, s1);
  gather_seg_k<<<N_NODES / 4, 256, 0, stream>>>(s1, offs, ssrc, Bg);
  vnew_k<<<rb, 256, 0, stream>>>(A, Bg, WAg, WBg, cg, Vout);
  proj_k<<<rb, 256, 0, stream>>>(Vout, W_S, b_S, PsP, PdP);
  edge_k<<<M_EDGES / 64, 256, 0, stream>>>(Eg, ssrc, sdst, eid, PsP, PdP, W_S, EoutP, statsE);
  col_stats_k<<<512, 256, 0, stream>>>(Vout, ND, statsV);
  finalize_k<<<1, 64, 0, stream>>>(statsV, 1.f / N_NODES, gammaV, betaV, scshV);
  finalize_k<<<1, 64, 0, stream>>>(statsE, 1.f / M_EDGES, gammaE, betaE, scshE);
  bn_apply_k<<<(int)((ND / 4 + 255) / 256), 256, 0, stream>>>(Vout, V, scshV, (int)(ND / 4));
  bn_apply_k<<<(M_EDGES * 16 + 255) / 256, 256, 0, stream>>>(EoutP, Eg, scshE, M_EDGES * 16);
}

// Round 8
// 851.788 us; speedup vs baseline: 1.1321x; 1.1321x over previous
//
#include <hip/hip_runtime.h>
#include <hip/hip_bf16.h>

#define N_NODES 50000
#define M_EDGES 800000
#define LEAKY_F 0.2f
#define BN_EPS 1e-5f
#define NEBLK (M_EDGES / 64)

__device__ __forceinline__ float leaky(float x) { return x >= 0.f ? x : LEAKY_F * x; }

// round-to-nearest-even f32 -> bf16 (finite inputs)
__device__ __forceinline__ unsigned f2bf(float f) {
  unsigned u = __float_as_uint(f);
  return (u + 0x7fffu + ((u >> 16) & 1u)) >> 16;
}
__device__ __forceinline__ unsigned packbf(float a, float b) {
  return (f2bf(b) << 16) | f2bf(a);
}
__device__ __forceinline__ float bflo(unsigned u) { return __uint_as_float(u << 16); }
__device__ __forceinline__ float bfhi(unsigned u) { return __uint_as_float(u & 0xffff0000u); }

// ================= CSR build =================
__global__ __launch_bounds__(256) void hist_k(const int* __restrict__ dst,
                                              int* __restrict__ counts) {
  int e = blockIdx.x * 256 + threadIdx.x;
  if (e < M_EDGES) atomicAdd(&counts[dst[e]], 1);
}

__global__ __launch_bounds__(256) void scan_k(const int* __restrict__ counts,
                                              int* __restrict__ offs,
                                              int* __restrict__ cursor) {
  __shared__ int chunk[256];
  const int CH = (N_NODES + 255) / 256;
  int tid = threadIdx.x;
  int beg = tid * CH, end = min(beg + CH, N_NODES);
  int s = 0;
  for (int i = beg; i < end; ++i) s += counts[i];
  chunk[tid] = s;
  __syncthreads();
  if (tid == 0) {
    int run = 0;
    for (int i = 0; i < 256; ++i) { int c = chunk[i]; chunk[i] = run; run += c; }
  }
  __syncthreads();
  int base = chunk[tid];
  for (int i = beg; i < end; ++i) {
    offs[i] = base;
    cursor[i] = base;
    base += counts[i];
  }
  if (tid == 0) offs[N_NODES] = M_EDGES;
}

// CSR fill: dst-sorted src list + original edge id + dst value per CSR slot
__global__ __launch_bounds__(256) void fill_k(const int* __restrict__ src,
                                              const int* __restrict__ dst,
                                              int* __restrict__ cursor,
                                              int* __restrict__ ssrc,
                                              int* __restrict__ eid,
                                              int* __restrict__ sdst) {
  int e = blockIdx.x * 256 + threadIdx.x;
  if (e >= M_EDGES) return;
  int d = dst[e];
  int p = atomicAdd(&cursor[d], 1);
  ssrc[p] = src[e];
  eid[p] = e;
  sdst[p] = d;
}

// ---- segment gather-sum, wave per node, 4x unrolled ----
__global__ __launch_bounds__(256) void gather_seg_k(const float* __restrict__ X,
                                                    const int* __restrict__ offs,
                                                    const int* __restrict__ ssrc,
                                                    float* __restrict__ O) {
  int n = blockIdx.x * 4 + (threadIdx.x >> 6);
  int j = threadIdx.x & 63;
  int beg = offs[n], end = offs[n + 1];
  float acc = 0.f;
  int i = beg;
  for (; i + 3 < end; i += 4) {
    int s0 = ssrc[i], s1 = ssrc[i + 1], s2 = ssrc[i + 2], s3 = ssrc[i + 3];
    float a = X[(size_t)s0 * 64 + j];
    float b = X[(size_t)s1 * 64 + j];
    float c = X[(size_t)s2 * 64 + j];
    float d = X[(size_t)s3 * 64 + j];
    acc += (a + b) + (c + d);
  }
  for (; i < end; ++i) acc += X[(size_t)ssrc[i] * 64 + j];
  O[(size_t)n * 64 + j] = acc;
}

// ================= weight-prep (algebraic collapse) =================
__global__ __launch_bounds__(256) void prep1_k(const float* __restrict__ W_ops,
                                               const float* __restrict__ W_cat,
                                               float* __restrict__ W12g,
                                               float* __restrict__ Wc12g) {
  __shared__ float Wa[4096], Wb[4096];
  int tid = threadIdx.x;
  const float *Am, *Bm, *Add;
  float* Out;
  if (blockIdx.x == 0) { Am = W_ops; Bm = W_ops + 8192; Add = W_ops + 4096; Out = W12g; }
  else { Am = W_ops + 16384; Bm = W_cat + 8192; Add = W_cat + 4096; Out = Wc12g; }
  for (int i = tid; i < 4096; i += 256) { Wa[i] = Am[i]; Wb[i] = Bm[i]; }
  __syncthreads();
  for (int t = 0; t < 16; ++t) {
    int o = tid + t * 256;
    int r = o >> 6, j = o & 63;
    float acc = Add[o];
#pragma unroll
    for (int k = 0; k < 64; ++k) acc = fmaf(Wa[r * 64 + k], Wb[k * 64 + j], acc);
    Out[o] = acc;
  }
}

__global__ __launch_bounds__(256) void prep2_k(const float* __restrict__ W_ops,
                                               const float* __restrict__ b_ops,
                                               const float* __restrict__ W_cat,
                                               const float* __restrict__ b_cat,
                                               const float* __restrict__ W12g,
                                               const float* __restrict__ Wc12g,
                                               float* __restrict__ WAg,
                                               float* __restrict__ WBg,
                                               float* __restrict__ cg) {
  __shared__ float M0[4096], M1[4096], M2[4096], M3[4096], M4[4096];
  __shared__ float bb[64];
  int tid = threadIdx.x;
  if (blockIdx.x == 0) {
    for (int i = tid; i < 4096; i += 256) {
      M0[i] = W_ops[i];
      M1[i] = W_cat[i];
      M2[i] = W12g[i];
      M3[i] = Wc12g[i];
    }
    __syncthreads();
    for (int t = 0; t < 16; ++t) {
      int o = tid + t * 256;
      int r = o >> 6, j = o & 63;
      float acc = 0.f;
#pragma unroll
      for (int k = 0; k < 64; ++k) {
        acc = fmaf(M0[r * 64 + k], M1[k * 64 + j], acc);
        acc = fmaf(M2[r * 64 + k], M3[k * 64 + j], acc);
      }
      WAg[o] = acc;
    }
  } else {
    for (int i = tid; i < 4096; i += 256) {
      M0[i] = W_ops[3 * 4096 + i];
      M1[i] = W_cat[8192 + i];
      M2[i] = W_ops[2 * 4096 + i];
      M3[i] = W_cat[i];
      M4[i] = Wc12g[i];
    }
    __syncthreads();
    for (int t = 0; t < 16; ++t) {
      int o = tid + t * 256;
      int r = o >> 6, j = o & 63;
      float acc = 0.f;
#pragma unroll
      for (int k = 0; k < 64; ++k) acc = fmaf(M0[r * 64 + k], M1[k * 64 + j], acc);
      WBg[o] = acc;
    }
    if (tid < 64) {
      int j = tid;
      float acc = b_ops[64 + j] + b_ops[128 + j];
#pragma unroll
      for (int k = 0; k < 64; ++k) acc = fmaf(b_ops[k], M2[k * 64 + j], acc);
      bb[j] = acc;
    }
    __syncthreads();
    if (tid < 64) {
      int j = tid;
      float acc = b_cat[j];
#pragma unroll
      for (int k = 0; k < 64; ++k) {
        acc = fmaf(b_ops[k], M3[k * 64 + j], acc);
        acc = fmaf(bb[k], M4[k * 64 + j], acc);
        acc = fmaf(b_ops[192 + k] + b_ops[256 + k], M1[k * 64 + j], acc);
      }
      cg[j] = acc;
    }
  }
}

// ================= row-register matmul kernels =================
__global__ __launch_bounds__(256) void rowmm1_k(const float* __restrict__ A,
                                                const float* __restrict__ W_ops,
                                                const float* __restrict__ b_ops,
                                                float* __restrict__ s1) {
  __shared__ float W[4096];
  __shared__ float bias[64];
  int tid = threadIdx.x;
  for (int i = tid; i < 4096; i += 256) W[i] = W_ops[i];
  if (tid < 64) bias[tid] = b_ops[tid];
  __syncthreads();
  int r = blockIdx.x * 256 + tid;
  if (r >= N_NODES) return;
  float x[64];
  const float4* Xr = reinterpret_cast<const float4*>(A + (size_t)r * 64);
#pragma unroll
  for (int q = 0; q < 16; ++q) {
    float4 v = Xr[q];
    x[q * 4] = v.x; x[q * 4 + 1] = v.y; x[q * 4 + 2] = v.z; x[q * 4 + 3] = v.w;
  }
  float4* Or = reinterpret_cast<float4*>(s1 + (size_t)r * 64);
  for (int j0 = 0; j0 < 64; j0 += 4) {
    float a0 = bias[j0], a1 = bias[j0 + 1], a2 = bias[j0 + 2], a3 = bias[j0 + 3];
#pragma unroll
    for (int k = 0; k < 64; ++k) {
      float4 w = *reinterpret_cast<const float4*>(&W[k * 64 + j0]);
      a0 = fmaf(x[k], w.x, a0);
      a1 = fmaf(x[k], w.y, a1);
      a2 = fmaf(x[k], w.z, a2);
      a3 = fmaf(x[k], w.w, a3);
    }
    Or[j0 >> 2] = make_float4(a0, a1, a2, a3);
  }
}

__global__ __launch_bounds__(256) void vnew_k(const float* __restrict__ A,
                                              const float* __restrict__ B,
                                              const float* __restrict__ WAg,
                                              const float* __restrict__ WBg,
                                              const float* __restrict__ cg,
                                              float* __restrict__ Vnew) {
  __shared__ float WA[4096], WB[4096];
  __shared__ float cb[64];
  int tid = threadIdx.x;
  for (int i = tid; i < 4096; i += 256) { WA[i] = WAg[i]; WB[i] = WBg[i]; }
  if (tid < 64) cb[tid] = cg[tid];
  __syncthreads();
  int r = blockIdx.x * 256 + tid;
  if (r >= N_NODES) return;
  float xa[64], xb[64];
  const float4* Ar = reinterpret_cast<const float4*>(A + (size_t)r * 64);
  const float4* Br = reinterpret_cast<const float4*>(B + (size_t)r * 64);
#pragma unroll
  for (int q = 0; q < 16; ++q) {
    float4 va = Ar[q];
    xa[q * 4] = va.x; xa[q * 4 + 1] = va.y; xa[q * 4 + 2] = va.z; xa[q * 4 + 3] = va.w;
    float4 vb = Br[q];
    xb[q * 4] = vb.x; xb[q * 4 + 1] = vb.y; xb[q * 4 + 2] = vb.z; xb[q * 4 + 3] = vb.w;
  }
  float4* Or = reinterpret_cast<float4*>(Vnew + (size_t)r * 64);
  for (int j0 = 0; j0 < 64; j0 += 4) {
    float a0 = cb[j0], a1 = cb[j0 + 1], a2 = cb[j0 + 2], a3 = cb[j0 + 3];
#pragma unroll
    for (int k = 0; k < 64; ++k) {
      float4 wa = *reinterpret_cast<const float4*>(&WA[k * 64 + j0]);
      a0 = fmaf(xa[k], wa.x, a0);
      a1 = fmaf(xa[k], wa.y, a1);
      a2 = fmaf(xa[k], wa.z, a2);
      a3 = fmaf(xa[k], wa.w, a3);
      float4 wb = *reinterpret_cast<const float4*>(&WB[k * 64 + j0]);
      a0 = fmaf(xb[k], wb.x, a0);
      a1 = fmaf(xb[k], wb.y, a1);
      a2 = fmaf(xb[k], wb.z, a2);
      a3 = fmaf(xb[k], wb.w, a3);
    }
    Or[j0 >> 2] = make_float4(a0, a1, a2, a3);
  }
}

// Ps/Pd written as packed bf16 pairs (row = 32 uints = 128 B)
__global__ __launch_bounds__(256) void proj_k(const float* __restrict__ Vnew,
                                              const float* __restrict__ W_S,
                                              const float* __restrict__ b_S,
                                              unsigned* __restrict__ PsP,
                                              unsigned* __restrict__ PdP) {
  __shared__ float W0s[4096], W2s[4096];
  __shared__ float bias[64];
  int tid = threadIdx.x;
  for (int i = tid; i < 4096; i += 256) { W0s[i] = W_S[i]; W2s[i] = W_S[8192 + i]; }
  if (tid < 64) bias[tid] = b_S[tid];
  __syncthreads();
  int r = blockIdx.x * 256 + tid;
  if (r >= N_NODES) return;
  float x[64];
  const float4* Xr = reinterpret_cast<const float4*>(Vnew + (size_t)r * 64);
#pragma unroll
  for (int q = 0; q < 16; ++q) {
    float4 v = Xr[q];
    x[q * 4] = v.x; x[q * 4 + 1] = v.y; x[q * 4 + 2] = v.z; x[q * 4 + 3] = v.w;
  }
  for (int j0 = 0; j0 < 64; j0 += 4) {
    float a0 = bias[j0], a1 = bias[j0 + 1], a2 = bias[j0 + 2], a3 = bias[j0 + 3];
    float d0 = 0.f, d1 = 0.f, d2 = 0.f, d3 = 0.f;
#pragma unroll
    for (int k = 0; k < 64; ++k) {
      float xk = x[k];
      float4 w = *reinterpret_cast<const float4*>(&W0s[k * 64 + j0]);
      a0 = fmaf(xk, w.x, a0);
      a1 = fmaf(xk, w.y, a1);
      a2 = fmaf(xk, w.z, a2);
      a3 = fmaf(xk, w.w, a3);
      float4 u = *reinterpret_cast<const float4*>(&W2s[k * 64 + j0]);
      d0 = fmaf(xk, u.x, d0);
      d1 = fmaf(xk, u.y, d1);
      d2 = fmaf(xk, u.z, d2);
      d3 = fmaf(xk, u.w, d3);
    }
    uint2 ps = make_uint2(packbf(a0, a1), packbf(a2, a3));
    uint2 pd = make_uint2(packbf(d0, d1), packbf(d2, d3));
    *reinterpret_cast<uint2*>(&PsP[(size_t)r * 32 + (j0 >> 1)]) = ps;
    *reinterpret_cast<uint2*>(&PdP[(size_t)r * 32 + (j0 >> 1)]) = pd;
  }
}

// ---- edge in dst-CSR order, cooperative row-granular gather; stats -> per-block
// NON-ATOMIC partial writes (the 1.6M global atomics were the 350us floor) ----
__global__ __launch_bounds__(256) void edge_k(
    const float* __restrict__ Eg, const int* __restrict__ ssrc, const int* __restrict__ sdst,
    const int* __restrict__ eid,
    const unsigned* __restrict__ PsP, const unsigned* __restrict__ PdP,
    const float* __restrict__ W_S, float* __restrict__ Eout,
    float* __restrict__ partials) {
  __shared__ unsigned Wt[64][33];
  __shared__ unsigned Ea[64][33];
  __shared__ float Spd[64][68];
  __shared__ int leid[64];
  __shared__ float ls[128];
  int tid = threadIdx.x;
  int e0 = blockIdx.x * 64;
  int l16 = tid & 15, g16 = tid >> 4;

  // phase A: issue gather row-loads into regs (latency overlaps staging)
  uint2 pa[4], pb[4];
#pragma unroll
  for (int rr = 0; rr < 4; ++rr) {
    int p = e0 + rr * 16 + g16;
    int s = ssrc[p], d = sdst[p];
    pa[rr] = *reinterpret_cast<const uint2*>(&PsP[(size_t)s * 32 + 2 * l16]);
    pb[rr] = *reinterpret_cast<const uint2*>(&PdP[(size_t)d * 32 + 2 * l16]);
  }
  if (tid < 64) leid[tid] = eid[e0 + tid];
  for (int q = tid; q < 2048; q += 256) {
    int k2 = q >> 6, j = q & 63;
    float w0 = W_S[4096 + (2 * k2) * 64 + j];
    float w1 = W_S[4096 + (2 * k2 + 1) * 64 + j];
    Wt[j][k2] = packbf(w0, w1);
  }
  if (tid < 128) ls[tid] = 0.f;
  __syncthreads();

  // phase B: stage leaky(E) (indirect rows) + write gathered sums to Spd
  for (int q = tid; q < 1024; q += 256) {
    int e = q >> 4, kq = q & 15;
    float4 vv = reinterpret_cast<const float4*>(Eg)[(size_t)leid[e] * 16 + kq];
    Ea[e][kq * 2]     = packbf(leaky(vv.x), leaky(vv.y));
    Ea[e][kq * 2 + 1] = packbf(leaky(vv.z), leaky(vv.w));
  }
#pragma unroll
  for (int rr = 0; rr < 4; ++rr) {
    int r = rr * 16 + g16;
    float4 f;
    f.x = bflo(pa[rr].x) + bflo(pb[rr].x);
    f.y = bfhi(pa[rr].x) + bfhi(pb[rr].x);
    f.z = bflo(pa[rr].y) + bflo(pb[rr].y);
    f.w = bfhi(pa[rr].y) + bfhi(pb[rr].y);
    *reinterpret_cast<float4*>(&Spd[r][4 * l16]) = f;
  }
  __syncthreads();

  int eq = tid & 15, cq = tid >> 4;
  int eb = eq * 4;
  float acc[4][4];
#pragma unroll
  for (int i = 0; i < 4; ++i) {
    float4 f = *reinterpret_cast<const float4*>(&Spd[eb + i][4 * cq]);
    acc[i][0] = f.x; acc[i][1] = f.y; acc[i][2] = f.z; acc[i][3] = f.w;
  }

#pragma unroll 4
  for (int k2 = 0; k2 < 32; ++k2) {
    float w0[4], w1[4];
#pragma unroll
    for (int c = 0; c < 4; ++c) {
      unsigned u = Wt[cq * 4 + c][k2];
      w0[c] = bflo(u);
      w1[c] = bfhi(u);
    }
#pragma unroll
    for (int i = 0; i < 4; ++i) {
      unsigned ue = Ea[eb + i][k2];
      float ev0 = bflo(ue), ev1 = bfhi(ue);
#pragma unroll
      for (int c = 0; c < 4; ++c) {
        acc[i][c] = fmaf(ev0, w0[c], acc[i][c]);
        acc[i][c] = fmaf(ev1, w1[c], acc[i][c]);
      }
    }
  }

  float s4[4] = {0.f, 0.f, 0.f, 0.f}, q4[4] = {0.f, 0.f, 0.f, 0.f};
#pragma unroll
  for (int i = 0; i < 4; ++i) {
    float4 st = make_float4(acc[i][0], acc[i][1], acc[i][2], acc[i][3]);
    reinterpret_cast<float4*>(Eout)[(size_t)leid[eb + i] * 16 + cq] = st;
#pragma unroll
    for (int c = 0; c < 4; ++c) {
      s4[c] += acc[i][c];
      q4[c] = fmaf(acc[i][c], acc[i][c], q4[c]);
    }
  }
#pragma unroll
  for (int off = 8; off; off >>= 1) {
#pragma unroll
    for (int c = 0; c < 4; ++c) {
      s4[c] += __shfl_xor(s4[c], off, 16);
      q4[c] += __shfl_xor(q4[c], off, 16);
    }
  }
  if (eq == 0) {
#pragma unroll
    for (int c = 0; c < 4; ++c) {
      atomicAdd(&ls[cq * 4 + c], s4[c]);
      atomicAdd(&ls[64 + cq * 4 + c], q4[c]);
    }
  }
  __syncthreads();
  if (tid < 128) partials[(size_t)blockIdx.x * 128 + tid] = ls[tid];
}

// ---- reduce per-block partials [NEBLK][128] -> stats[128] ----
__global__ __launch_bounds__(256) void reduce_stats_k(const float* __restrict__ partials,
                                                      float* __restrict__ stats) {
  __shared__ float ls[128];
  int tid = threadIdx.x;
  if (tid < 128) ls[tid] = 0.f;
  __syncthreads();
  int c = tid & 127;
  int half = tid >> 7;
  float s = 0.f;
  for (int r = blockIdx.x * 2 + half; r < NEBLK; r += 2 * gridDim.x) {
    s += partials[(size_t)r * 128 + c];
  }
  atomicAdd(&ls[c], s);
  __syncthreads();
  if (tid < 128) atomicAdd(&stats[tid], ls[tid]);
}

// ---- per-column sum / sumsq (for V side) ----
__global__ __launch_bounds__(256) void col_stats_k(
    const float* __restrict__ X, size_t nelem, float* __restrict__ sums) {
  __shared__ float ls[128];
  int tid = threadIdx.x;
  if (tid < 128) ls[tid] = 0.f;
  __syncthreads();
  int j = tid & 63;
  float s = 0.f, ss = 0.f;
  size_t stride = (size_t)gridDim.x * blockDim.x;
  for (size_t i = (size_t)blockIdx.x * blockDim.x + tid; i < nelem; i += stride) {
    float x = X[i];
    s += x;
    ss = fmaf(x, x, ss);
  }
  atomicAdd(&ls[j], s);
  atomicAdd(&ls[64 + j], ss);
  __syncthreads();
  if (tid < 128) atomicAdd(&sums[tid], ls[tid]);
}

__global__ void finalize_k(const float* __restrict__ sums, float inv_n,
                           const float* __restrict__ gamma, const float* __restrict__ beta,
                           float* __restrict__ sc_shift) {
  int j = threadIdx.x;
  float mu = sums[j] * inv_n;
  float var = sums[64 + j] * inv_n - mu * mu;
  float sc = gamma[j] * rsqrtf(var + BN_EPS);
  sc_shift[j] = sc;
  sc_shift[64 + j] = beta[j] - mu * sc;
}

__global__ __launch_bounds__(256) void bn_apply_k(
    float* __restrict__ X, const float* __restrict__ resid,
    const float* __restrict__ sc_shift, int n4) {
  int i = blockIdx.x * blockDim.x + threadIdx.x;
  if (i >= n4) return;
  int jq = i & 15;
  float4 x = reinterpret_cast<float4*>(X)[i];
  float4 r = reinterpret_cast<const float4*>(resid)[i];
  float4 sc = reinterpret_cast<const float4*>(sc_shift)[jq];
  float4 sh = reinterpret_cast<const float4*>(sc_shift + 64)[jq];
  float4 y;
  y.x = leaky(fmaf(x.x, sc.x, sh.x)) + r.x;
  y.y = leaky(fmaf(x.y, sc.y, sh.y)) + r.y;
  y.z = leaky(fmaf(x.z, sc.z, sh.z)) + r.z;
  y.w = leaky(fmaf(x.w, sc.w, sh.w)) + r.w;
  reinterpret_cast<float4*>(X)[i] = y;
}

extern "C" void kernel_launch(void* const* d_in, const int* in_sizes, int n_in,
                              void* d_out, int out_size, void* d_ws, size_t ws_size,
                              hipStream_t stream) {
  const float* V      = (const float*)d_in[0];
  const float* Eg     = (const float*)d_in[1];
  const int*   src    = (const int*)d_in[2];
  const int*   dst    = (const int*)d_in[3];
  const float* W_ops  = (const float*)d_in[4];
  const float* b_ops  = (const float*)d_in[5];
  const float* W_cat  = (const float*)d_in[6];
  const float* b_cat  = (const float*)d_in[7];
  const float* W_S    = (const float*)d_in[8];
  const float* b_S    = (const float*)d_in[9];
  const float* gammaV = (const float*)d_in[10];
  const float* betaV  = (const float*)d_in[11];
  const float* gammaE = (const float*)d_in[12];
  const float* betaE  = (const float*)d_in[13];

  float* ws = (float*)d_ws;
  const size_t ND = (size_t)N_NODES * 64;
  float* A    = ws;
  float* s1   = ws + ND;
  float* Bg   = ws + 2 * ND;
  unsigned* PsP = (unsigned*)(ws + 3 * ND);
  unsigned* PdP = (unsigned*)(ws + 4 * ND);
  float* xb   = ws + 5 * ND;
  float* W12g  = xb;
  float* Wc12g = xb + 4096;
  float* WAg   = xb + 8192;
  float* WBg   = xb + 12288;
  float* cg    = xb + 16384;
  float* statsV = xb + 16448;
  float* statsE = statsV + 128;
  float* scshV  = statsV + 256;
  float* scshE  = statsV + 384;
  int* counts = (int*)(statsV + 512);
  int* offs   = counts + N_NODES;
  int* cursor = offs + N_NODES + 1;
  int* ssrc   = cursor + N_NODES;
  int* eid    = ssrc + M_EDGES;
  int* sdst   = eid + M_EDGES;
  float* partials = (float*)(sdst + M_EDGES);   // NEBLK*128 floats = 6.4 MB

  float* Vout  = (float*)d_out;
  float* EoutP = Vout + ND;

  hipMemsetAsync(counts, 0, N_NODES * sizeof(int), stream);
  hipMemsetAsync(statsV, 0, 256 * sizeof(float), stream);

  const int eb = (M_EDGES + 255) / 256;
  const int rb = (N_NODES + 255) / 256;
  prep1_k<<<2, 256, 0, stream>>>(W_ops, W_cat, W12g, Wc12g);
  prep2_k<<<2, 256, 0, stream>>>(W_ops, b_ops, W_cat, b_cat, W12g, Wc12g, WAg, WBg, cg);
  hist_k<<<eb, 256, 0, stream>>>(dst, counts);
  scan_k<<<1, 256, 0, stream>>>(counts, offs, cursor);
  fill_k<<<eb, 256, 0, stream>>>(src, dst, cursor, ssrc, eid, sdst);

  gather_seg_k<<<N_NODES / 4, 256, 0, stream>>>(V, offs, ssrc, A);
  rowmm1_k<<<rb, 256, 0, stream>>>(A, W_ops, b_ops, s1);
  gather_seg_k<<<N_NODES / 4, 256, 0, stream>>>(s1, offs, ssrc, Bg);
  vnew_k<<<rb, 256, 0, stream>>>(A, Bg, WAg, WBg, cg, Vout);
  proj_k<<<rb, 256, 0, stream>>>(Vout, W_S, b_S, PsP, PdP);
  edge_k<<<NEBLK, 256, 0, stream>>>(Eg, ssrc, sdst, eid, PsP, PdP, W_S, EoutP, partials);
  reduce_stats_k<<<64, 256, 0, stream>>>(partials, statsE);
  col_stats_k<<<512, 256, 0, stream>>>(Vout, ND, statsV);
  finalize_k<<<1, 64, 0, stream>>>(statsV, 1.f / N_NODES, gammaV, betaV, scshV);
  finalize_k<<<1, 64, 0, stream>>>(statsE, 1.f / M_EDGES, gammaE, betaE, scshE);
  bn_apply_k<<<(int)((ND / 4 + 255) / 256), 256, 0, stream>>>(Vout, V, scshV, (int)(ND / 4));
  bn_apply_k<<<(M_EDGES * 16 + 255) / 256, 256, 0, stream>>>(EoutP, Eg, scshE, M_EDGES * 16);
}

// Round 9
// 849.038 us; speedup vs baseline: 1.1357x; 1.0032x over previous
//
#include <hip/hip_runtime.h>
#include <hip/hip_bf16.h>

#define N_NODES 50000
#define M_EDGES 800000
#define LEAKY_F 0.2f
#define BN_EPS 1e-5f
#define NEBLK (M_EDGES / 64)

__device__ __forceinline__ float leaky(float x) { return x >= 0.f ? x : LEAKY_F * x; }

// round-to-nearest-even f32 -> bf16 (finite inputs)
__device__ __forceinline__ unsigned f2bf(float f) {
  unsigned u = __float_as_uint(f);
  return (u + 0x7fffu + ((u >> 16) & 1u)) >> 16;
}
__device__ __forceinline__ unsigned packbf(float a, float b) {
  return (f2bf(b) << 16) | f2bf(a);
}
__device__ __forceinline__ float bflo(unsigned u) { return __uint_as_float(u << 16); }
__device__ __forceinline__ float bfhi(unsigned u) { return __uint_as_float(u & 0xffff0000u); }

// ================= CSR build (for gather_seg only) =================
__global__ __launch_bounds__(256) void hist_k(const int* __restrict__ dst,
                                              int* __restrict__ counts) {
  int e = blockIdx.x * 256 + threadIdx.x;
  if (e < M_EDGES) atomicAdd(&counts[dst[e]], 1);
}

__global__ __launch_bounds__(256) void scan_k(const int* __restrict__ counts,
                                              int* __restrict__ offs,
                                              int* __restrict__ cursor) {
  __shared__ int chunk[256];
  const int CH = (N_NODES + 255) / 256;
  int tid = threadIdx.x;
  int beg = tid * CH, end = min(beg + CH, N_NODES);
  int s = 0;
  for (int i = beg; i < end; ++i) s += counts[i];
  chunk[tid] = s;
  __syncthreads();
  if (tid == 0) {
    int run = 0;
    for (int i = 0; i < 256; ++i) { int c = chunk[i]; chunk[i] = run; run += c; }
  }
  __syncthreads();
  int base = chunk[tid];
  for (int i = beg; i < end; ++i) {
    offs[i] = base;
    cursor[i] = base;
    base += counts[i];
  }
  if (tid == 0) offs[N_NODES] = M_EDGES;
}

__global__ __launch_bounds__(256) void fill_k(const int* __restrict__ src,
                                              const int* __restrict__ dst,
                                              int* __restrict__ cursor,
                                              int* __restrict__ ssrc) {
  int e = blockIdx.x * 256 + threadIdx.x;
  if (e >= M_EDGES) return;
  int p = atomicAdd(&cursor[dst[e]], 1);
  ssrc[p] = src[e];
}

// ---- segment gather-sum, wave per node, 4x unrolled ----
__global__ __launch_bounds__(256) void gather_seg_k(const float* __restrict__ X,
                                                    const int* __restrict__ offs,
                                                    const int* __restrict__ ssrc,
                                                    float* __restrict__ O) {
  int n = blockIdx.x * 4 + (threadIdx.x >> 6);
  int j = threadIdx.x & 63;
  int beg = offs[n], end = offs[n + 1];
  float acc = 0.f;
  int i = beg;
  for (; i + 3 < end; i += 4) {
    int s0 = ssrc[i], s1 = ssrc[i + 1], s2 = ssrc[i + 2], s3 = ssrc[i + 3];
    float a = X[(size_t)s0 * 64 + j];
    float b = X[(size_t)s1 * 64 + j];
    float c = X[(size_t)s2 * 64 + j];
    float d = X[(size_t)s3 * 64 + j];
    acc += (a + b) + (c + d);
  }
  for (; i < end; ++i) acc += X[(size_t)ssrc[i] * 64 + j];
  O[(size_t)n * 64 + j] = acc;
}

// ================= weight-prep (algebraic collapse) =================
__global__ __launch_bounds__(256) void prep1_k(const float* __restrict__ W_ops,
                                               const float* __restrict__ W_cat,
                                               float* __restrict__ W12g,
                                               float* __restrict__ Wc12g) {
  __shared__ float Wa[4096], Wb[4096];
  int tid = threadIdx.x;
  const float *Am, *Bm, *Add;
  float* Out;
  if (blockIdx.x == 0) { Am = W_ops; Bm = W_ops + 8192; Add = W_ops + 4096; Out = W12g; }
  else { Am = W_ops + 16384; Bm = W_cat + 8192; Add = W_cat + 4096; Out = Wc12g; }
  for (int i = tid; i < 4096; i += 256) { Wa[i] = Am[i]; Wb[i] = Bm[i]; }
  __syncthreads();
  for (int t = 0; t < 16; ++t) {
    int o = tid + t * 256;
    int r = o >> 6, j = o & 63;
    float acc = Add[o];
#pragma unroll
    for (int k = 0; k < 64; ++k) acc = fmaf(Wa[r * 64 + k], Wb[k * 64 + j], acc);
    Out[o] = acc;
  }
}

__global__ __launch_bounds__(256) void prep2_k(const float* __restrict__ W_ops,
                                               const float* __restrict__ b_ops,
                                               const float* __restrict__ W_cat,
                                               const float* __restrict__ b_cat,
                                               const float* __restrict__ W12g,
                                               const float* __restrict__ Wc12g,
                                               float* __restrict__ WAg,
                                               float* __restrict__ WBg,
                                               float* __restrict__ cg) {
  __shared__ float M0[4096], M1[4096], M2[4096], M3[4096], M4[4096];
  __shared__ float bb[64];
  int tid = threadIdx.x;
  if (blockIdx.x == 0) {
    for (int i = tid; i < 4096; i += 256) {
      M0[i] = W_ops[i];
      M1[i] = W_cat[i];
      M2[i] = W12g[i];
      M3[i] = Wc12g[i];
    }
    __syncthreads();
    for (int t = 0; t < 16; ++t) {
      int o = tid + t * 256;
      int r = o >> 6, j = o & 63;
      float acc = 0.f;
#pragma unroll
      for (int k = 0; k < 64; ++k) {
        acc = fmaf(M0[r * 64 + k], M1[k * 64 + j], acc);
        acc = fmaf(M2[r * 64 + k], M3[k * 64 + j], acc);
      }
      WAg[o] = acc;
    }
  } else {
    for (int i = tid; i < 4096; i += 256) {
      M0[i] = W_ops[3 * 4096 + i];
      M1[i] = W_cat[8192 + i];
      M2[i] = W_ops[2 * 4096 + i];
      M3[i] = W_cat[i];
      M4[i] = Wc12g[i];
    }
    __syncthreads();
    for (int t = 0; t < 16; ++t) {
      int o = tid + t * 256;
      int r = o >> 6, j = o & 63;
      float acc = 0.f;
#pragma unroll
      for (int k = 0; k < 64; ++k) acc = fmaf(M0[r * 64 + k], M1[k * 64 + j], acc);
      WBg[o] = acc;
    }
    if (tid < 64) {
      int j = tid;
      float acc = b_ops[64 + j] + b_ops[128 + j];
#pragma unroll
      for (int k = 0; k < 64; ++k) acc = fmaf(b_ops[k], M2[k * 64 + j], acc);
      bb[j] = acc;
    }
    __syncthreads();
    if (tid < 64) {
      int j = tid;
      float acc = b_cat[j];
#pragma unroll
      for (int k = 0; k < 64; ++k) {
        acc = fmaf(b_ops[k], M3[k * 64 + j], acc);
        acc = fmaf(bb[k], M4[k * 64 + j], acc);
        acc = fmaf(b_ops[192 + k] + b_ops[256 + k], M1[k * 64 + j], acc);
      }
      cg[j] = acc;
    }
  }
}

// ================= row-register matmul kernels =================
__global__ __launch_bounds__(256) void rowmm1_k(const float* __restrict__ A,
                                                const float* __restrict__ W_ops,
                                                const float* __restrict__ b_ops,
                                                float* __restrict__ s1) {
  __shared__ float W[4096];
  __shared__ float bias[64];
  int tid = threadIdx.x;
  for (int i = tid; i < 4096; i += 256) W[i] = W_ops[i];
  if (tid < 64) bias[tid] = b_ops[tid];
  __syncthreads();
  int r = blockIdx.x * 256 + tid;
  if (r >= N_NODES) return;
  float x[64];
  const float4* Xr = reinterpret_cast<const float4*>(A + (size_t)r * 64);
#pragma unroll
  for (int q = 0; q < 16; ++q) {
    float4 v = Xr[q];
    x[q * 4] = v.x; x[q * 4 + 1] = v.y; x[q * 4 + 2] = v.z; x[q * 4 + 3] = v.w;
  }
  float4* Or = reinterpret_cast<float4*>(s1 + (size_t)r * 64);
  for (int j0 = 0; j0 < 64; j0 += 4) {
    float a0 = bias[j0], a1 = bias[j0 + 1], a2 = bias[j0 + 2], a3 = bias[j0 + 3];
#pragma unroll
    for (int k = 0; k < 64; ++k) {
      float4 w = *reinterpret_cast<const float4*>(&W[k * 64 + j0]);
      a0 = fmaf(x[k], w.x, a0);
      a1 = fmaf(x[k], w.y, a1);
      a2 = fmaf(x[k], w.z, a2);
      a3 = fmaf(x[k], w.w, a3);
    }
    Or[j0 >> 2] = make_float4(a0, a1, a2, a3);
  }
}

__global__ __launch_bounds__(256) void vnew_k(const float* __restrict__ A,
                                              const float* __restrict__ B,
                                              const float* __restrict__ WAg,
                                              const float* __restrict__ WBg,
                                              const float* __restrict__ cg,
                                              float* __restrict__ Vnew) {
  __shared__ float WA[4096], WB[4096];
  __shared__ float cb[64];
  int tid = threadIdx.x;
  for (int i = tid; i < 4096; i += 256) { WA[i] = WAg[i]; WB[i] = WBg[i]; }
  if (tid < 64) cb[tid] = cg[tid];
  __syncthreads();
  int r = blockIdx.x * 256 + tid;
  if (r >= N_NODES) return;
  float xa[64], xb[64];
  const float4* Ar = reinterpret_cast<const float4*>(A + (size_t)r * 64);
  const float4* Br = reinterpret_cast<const float4*>(B + (size_t)r * 64);
#pragma unroll
  for (int q = 0; q < 16; ++q) {
    float4 va = Ar[q];
    xa[q * 4] = va.x; xa[q * 4 + 1] = va.y; xa[q * 4 + 2] = va.z; xa[q * 4 + 3] = va.w;
    float4 vb = Br[q];
    xb[q * 4] = vb.x; xb[q * 4 + 1] = vb.y; xb[q * 4 + 2] = vb.z; xb[q * 4 + 3] = vb.w;
  }
  float4* Or = reinterpret_cast<float4*>(Vnew + (size_t)r * 64);
  for (int j0 = 0; j0 < 64; j0 += 4) {
    float a0 = cb[j0], a1 = cb[j0 + 1], a2 = cb[j0 + 2], a3 = cb[j0 + 3];
#pragma unroll
    for (int k = 0; k < 64; ++k) {
      float4 wa = *reinterpret_cast<const float4*>(&WA[k * 64 + j0]);
      a0 = fmaf(xa[k], wa.x, a0);
      a1 = fmaf(xa[k], wa.y, a1);
      a2 = fmaf(xa[k], wa.z, a2);
      a3 = fmaf(xa[k], wa.w, a3);
      float4 wb = *reinterpret_cast<const float4*>(&WB[k * 64 + j0]);
      a0 = fmaf(xb[k], wb.x, a0);
      a1 = fmaf(xb[k], wb.y, a1);
      a2 = fmaf(xb[k], wb.z, a2);
      a3 = fmaf(xb[k], wb.w, a3);
    }
    Or[j0 >> 2] = make_float4(a0, a1, a2, a3);
  }
}

// Ps/Pd written as packed bf16 pairs (row = 32 uints = 128 B)
__global__ __launch_bounds__(256) void proj_k(const float* __restrict__ Vnew,
                                              const float* __restrict__ W_S,
                                              const float* __restrict__ b_S,
                                              unsigned* __restrict__ PsP,
                                              unsigned* __restrict__ PdP) {
  __shared__ float W0s[4096], W2s[4096];
  __shared__ float bias[64];
  int tid = threadIdx.x;
  for (int i = tid; i < 4096; i += 256) { W0s[i] = W_S[i]; W2s[i] = W_S[8192 + i]; }
  if (tid < 64) bias[tid] = b_S[tid];
  __syncthreads();
  int r = blockIdx.x * 256 + tid;
  if (r >= N_NODES) return;
  float x[64];
  const float4* Xr = reinterpret_cast<const float4*>(Vnew + (size_t)r * 64);
#pragma unroll
  for (int q = 0; q < 16; ++q) {
    float4 v = Xr[q];
    x[q * 4] = v.x; x[q * 4 + 1] = v.y; x[q * 4 + 2] = v.z; x[q * 4 + 3] = v.w;
  }
  for (int j0 = 0; j0 < 64; j0 += 4) {
    float a0 = bias[j0], a1 = bias[j0 + 1], a2 = bias[j0 + 2], a3 = bias[j0 + 3];
    float d0 = 0.f, d1 = 0.f, d2 = 0.f, d3 = 0.f;
#pragma unroll
    for (int k = 0; k < 64; ++k) {
      float xk = x[k];
      float4 w = *reinterpret_cast<const float4*>(&W0s[k * 64 + j0]);
      a0 = fmaf(xk, w.x, a0);
      a1 = fmaf(xk, w.y, a1);
      a2 = fmaf(xk, w.z, a2);
      a3 = fmaf(xk, w.w, a3);
      float4 u = *reinterpret_cast<const float4*>(&W2s[k * 64 + j0]);
      d0 = fmaf(xk, u.x, d0);
      d1 = fmaf(xk, u.y, d1);
      d2 = fmaf(xk, u.z, d2);
      d3 = fmaf(xk, u.w, d3);
    }
    uint2 ps = make_uint2(packbf(a0, a1), packbf(a2, a3));
    uint2 pd = make_uint2(packbf(d0, d1), packbf(d2, d3));
    *reinterpret_cast<uint2*>(&PsP[(size_t)r * 32 + (j0 >> 1)]) = ps;
    *reinterpret_cast<uint2*>(&PdP[(size_t)r * 32 + (j0 >> 1)]) = pd;
  }
}

// ---- edge in ORIGINAL order (sequential Eg read / Eout write), cooperative
// row-granular bf16 gathers of Ps/Pd; non-atomic per-block stats partials ----
__global__ __launch_bounds__(256) void edge_k(
    const float* __restrict__ Eg, const int* __restrict__ src, const int* __restrict__ dst,
    const unsigned* __restrict__ PsP, const unsigned* __restrict__ PdP,
    const float* __restrict__ W_S, float* __restrict__ Eout,
    float* __restrict__ partials) {
  __shared__ unsigned Wt[64][33];
  __shared__ unsigned Ea[64][33];
  __shared__ float Spd[64][68];
  __shared__ float ls[128];
  int tid = threadIdx.x;
  int e0 = blockIdx.x * 64;
  int l16 = tid & 15, g16 = tid >> 4;

  // phase A: issue gather row-loads into regs (latency overlaps staging)
  uint2 pa[4], pb[4];
#pragma unroll
  for (int rr = 0; rr < 4; ++rr) {
    int p = e0 + rr * 16 + g16;
    int s = src[p], d = dst[p];
    pa[rr] = *reinterpret_cast<const uint2*>(&PsP[(size_t)s * 32 + 2 * l16]);
    pb[rr] = *reinterpret_cast<const uint2*>(&PdP[(size_t)d * 32 + 2 * l16]);
  }
  for (int q = tid; q < 2048; q += 256) {
    int k2 = q >> 6, j = q & 63;
    float w0 = W_S[4096 + (2 * k2) * 64 + j];
    float w1 = W_S[4096 + (2 * k2 + 1) * 64 + j];
    Wt[j][k2] = packbf(w0, w1);
  }
  if (tid < 128) ls[tid] = 0.f;
  // stage leaky(E) rows (sequential), bf16-packed
  for (int q = tid; q < 1024; q += 256) {
    int e = q >> 4, kq = q & 15;
    float4 vv = reinterpret_cast<const float4*>(Eg)[(size_t)(e0 + e) * 16 + kq];
    Ea[e][kq * 2]     = packbf(leaky(vv.x), leaky(vv.y));
    Ea[e][kq * 2 + 1] = packbf(leaky(vv.z), leaky(vv.w));
  }
  // write gathered sums to Spd
#pragma unroll
  for (int rr = 0; rr < 4; ++rr) {
    int r = rr * 16 + g16;
    float4 f;
    f.x = bflo(pa[rr].x) + bflo(pb[rr].x);
    f.y = bfhi(pa[rr].x) + bfhi(pb[rr].x);
    f.z = bflo(pa[rr].y) + bflo(pb[rr].y);
    f.w = bfhi(pa[rr].y) + bfhi(pb[rr].y);
    *reinterpret_cast<float4*>(&Spd[r][4 * l16]) = f;
  }
  __syncthreads();

  int eq = tid & 15, cq = tid >> 4;
  int eb = eq * 4;
  float acc[4][4];
#pragma unroll
  for (int i = 0; i < 4; ++i) {
    float4 f = *reinterpret_cast<const float4*>(&Spd[eb + i][4 * cq]);
    acc[i][0] = f.x; acc[i][1] = f.y; acc[i][2] = f.z; acc[i][3] = f.w;
  }

#pragma unroll 4
  for (int k2 = 0; k2 < 32; ++k2) {
    float w0[4], w1[4];
#pragma unroll
    for (int c = 0; c < 4; ++c) {
      unsigned u = Wt[cq * 4 + c][k2];
      w0[c] = bflo(u);
      w1[c] = bfhi(u);
    }
#pragma unroll
    for (int i = 0; i < 4; ++i) {
      unsigned ue = Ea[eb + i][k2];
      float ev0 = bflo(ue), ev1 = bfhi(ue);
#pragma unroll
      for (int c = 0; c < 4; ++c) {
        acc[i][c] = fmaf(ev0, w0[c], acc[i][c]);
        acc[i][c] = fmaf(ev1, w1[c], acc[i][c]);
      }
    }
  }

  float s4[4] = {0.f, 0.f, 0.f, 0.f}, q4[4] = {0.f, 0.f, 0.f, 0.f};
#pragma unroll
  for (int i = 0; i < 4; ++i) {
    float4 st = make_float4(acc[i][0], acc[i][1], acc[i][2], acc[i][3]);
    reinterpret_cast<float4*>(Eout)[(size_t)(e0 + eb + i) * 16 + cq] = st;
#pragma unroll
    for (int c = 0; c < 4; ++c) {
      s4[c] += acc[i][c];
      q4[c] = fmaf(acc[i][c], acc[i][c], q4[c]);
    }
  }
#pragma unroll
  for (int off = 8; off; off >>= 1) {
#pragma unroll
    for (int c = 0; c < 4; ++c) {
      s4[c] += __shfl_xor(s4[c], off, 16);
      q4[c] += __shfl_xor(q4[c], off, 16);
    }
  }
  if (eq == 0) {
#pragma unroll
    for (int c = 0; c < 4; ++c) {
      atomicAdd(&ls[cq * 4 + c], s4[c]);
      atomicAdd(&ls[64 + cq * 4 + c], q4[c]);
    }
  }
  __syncthreads();
  if (tid < 128) partials[(size_t)blockIdx.x * 128 + tid] = ls[tid];
}

// ---- reduce per-block partials [NEBLK][128] -> stats[128] ----
__global__ __launch_bounds__(256) void reduce_stats_k(const float* __restrict__ partials,
                                                      float* __restrict__ stats) {
  __shared__ float ls[128];
  int tid = threadIdx.x;
  if (tid < 128) ls[tid] = 0.f;
  __syncthreads();
  int c = tid & 127;
  int half = tid >> 7;
  float s = 0.f;
  for (int r = blockIdx.x * 2 + half; r < NEBLK; r += 2 * gridDim.x) {
    s += partials[(size_t)r * 128 + c];
  }
  atomicAdd(&ls[c], s);
  __syncthreads();
  if (tid < 128) atomicAdd(&stats[tid], ls[tid]);
}

// ---- per-column sum / sumsq (for V side) ----
__global__ __launch_bounds__(256) void col_stats_k(
    const float* __restrict__ X, size_t nelem, float* __restrict__ sums) {
  __shared__ float ls[128];
  int tid = threadIdx.x;
  if (tid < 128) ls[tid] = 0.f;
  __syncthreads();
  int j = tid & 63;
  float s = 0.f, ss = 0.f;
  size_t stride = (size_t)gridDim.x * blockDim.x;
  for (size_t i = (size_t)blockIdx.x * blockDim.x + tid; i < nelem; i += stride) {
    float x = X[i];
    s += x;
    ss = fmaf(x, x, ss);
  }
  atomicAdd(&ls[j], s);
  atomicAdd(&ls[64 + j], ss);
  __syncthreads();
  if (tid < 128) atomicAdd(&sums[tid], ls[tid]);
}

__global__ void finalize_k(const float* __restrict__ sums, float inv_n,
                           const float* __restrict__ gamma, const float* __restrict__ beta,
                           float* __restrict__ sc_shift) {
  int j = threadIdx.x;
  float mu = sums[j] * inv_n;
  float var = sums[64 + j] * inv_n - mu * mu;
  float sc = gamma[j] * rsqrtf(var + BN_EPS);
  sc_shift[j] = sc;
  sc_shift[64 + j] = beta[j] - mu * sc;
}

__global__ __launch_bounds__(256) void bn_apply_k(
    float* __restrict__ X, const float* __restrict__ resid,
    const float* __restrict__ sc_shift, int n4) {
  int i = blockIdx.x * blockDim.x + threadIdx.x;
  if (i >= n4) return;
  int jq = i & 15;
  float4 x = reinterpret_cast<float4*>(X)[i];
  float4 r = reinterpret_cast<const float4*>(resid)[i];
  float4 sc = reinterpret_cast<const float4*>(sc_shift)[jq];
  float4 sh = reinterpret_cast<const float4*>(sc_shift + 64)[jq];
  float4 y;
  y.x = leaky(fmaf(x.x, sc.x, sh.x)) + r.x;
  y.y = leaky(fmaf(x.y, sc.y, sh.y)) + r.y;
  y.z = leaky(fmaf(x.z, sc.z, sh.z)) + r.z;
  y.w = leaky(fmaf(x.w, sc.w, sh.w)) + r.w;
  reinterpret_cast<float4*>(X)[i] = y;
}

extern "C" void kernel_launch(void* const* d_in, const int* in_sizes, int n_in,
                              void* d_out, int out_size, void* d_ws, size_t ws_size,
                              hipStream_t stream) {
  const float* V      = (const float*)d_in[0];
  const float* Eg     = (const float*)d_in[1];
  const int*   src    = (const int*)d_in[2];
  const int*   dst    = (const int*)d_in[3];
  const float* W_ops  = (const float*)d_in[4];
  const float* b_ops  = (const float*)d_in[5];
  const float* W_cat  = (const float*)d_in[6];
  const float* b_cat  = (const float*)d_in[7];
  const float* W_S    = (const float*)d_in[8];
  const float* b_S    = (const float*)d_in[9];
  const float* gammaV = (const float*)d_in[10];
  const float* betaV  = (const float*)d_in[11];
  const float* gammaE = (const float*)d_in[12];
  const float* betaE  = (const float*)d_in[13];

  float* ws = (float*)d_ws;
  const size_t ND = (size_t)N_NODES * 64;
  float* A    = ws;
  float* s1   = ws + ND;
  float* Bg   = ws + 2 * ND;
  unsigned* PsP = (unsigned*)(ws + 3 * ND);
  unsigned* PdP = (unsigned*)(ws + 4 * ND);
  float* xb   = ws + 5 * ND;
  float* W12g  = xb;
  float* Wc12g = xb + 4096;
  float* WAg   = xb + 8192;
  float* WBg   = xb + 12288;
  float* cg    = xb + 16384;
  float* statsV = xb + 16448;
  float* statsE = statsV + 128;
  float* scshV  = statsV + 256;
  float* scshE  = statsV + 384;
  int* counts = (int*)(statsV + 512);
  int* offs   = counts + N_NODES;
  int* cursor = offs + N_NODES + 1;
  int* ssrc   = cursor + N_NODES;
  float* partials = (float*)(ssrc + M_EDGES);   // NEBLK*128 floats = 6.4 MB

  float* Vout  = (float*)d_out;
  float* EoutP = Vout + ND;

  hipMemsetAsync(counts, 0, N_NODES * sizeof(int), stream);
  hipMemsetAsync(statsV, 0, 256 * sizeof(float), stream);

  const int eb = (M_EDGES + 255) / 256;
  const int rb = (N_NODES + 255) / 256;
  prep1_k<<<2, 256, 0, stream>>>(W_ops, W_cat, W12g, Wc12g);
  prep2_k<<<2, 256, 0, stream>>>(W_ops, b_ops, W_cat, b_cat, W12g, Wc12g, WAg, WBg, cg);
  hist_k<<<eb, 256, 0, stream>>>(dst, counts);
  scan_k<<<1, 256, 0, stream>>>(counts, offs, cursor);
  fill_k<<<eb, 256, 0, stream>>>(src, dst, cursor, ssrc);

  gather_seg_k<<<N_NODES / 4, 256, 0, stream>>>(V, offs, ssrc, A);
  rowmm1_k<<<rb, 256, 0, stream>>>(A, W_ops, b_ops, s1);
  gather_seg_k<<<N_NODES / 4, 256, 0, stream>>>(s1, offs, ssrc, Bg);
  vnew_k<<<rb, 256, 0, stream>>>(A, Bg, WAg, WBg, cg, Vout);
  proj_k<<<rb, 256, 0, stream>>>(Vout, W_S, b_S, PsP, PdP);
  edge_k<<<NEBLK, 256, 0, stream>>>(Eg, src, dst, PsP, PdP, W_S, EoutP, partials);
  reduce_stats_k<<<64, 256, 0, stream>>>(partials, statsE);
  col_stats_k<<<512, 256, 0, stream>>>(Vout, ND, statsV);
  finalize_k<<<1, 64, 0, stream>>>(statsV, 1.f / N_NODES, gammaV, betaV, scshV);
  finalize_k<<<1, 64, 0, stream>>>(statsE, 1.f / M_EDGES, gammaE, betaE, scshE);
  bn_apply_k<<<(int)((ND / 4 + 255) / 256), 256, 0, stream>>>(Vout, V, scshV, (int)(ND / 4));
  bn_apply_k<<<(M_EDGES * 16 + 255) / 256, 256, 0, stream>>>(EoutP, Eg, scshE, M_EDGES * 16);
}